// Round 1
// baseline (781.522 us; speedup 1.0000x reference)
//
#include <hip/hip_runtime.h>
#include <stdint.h>

#define NB 4
#define NS 2048
#define ND 1024
#define NH 16
#define EPSN 0.01f

typedef short bf16x8 __attribute__((ext_vector_type(8)));
typedef float f32x4 __attribute__((ext_vector_type(4)));

__device__ __forceinline__ float bf2f(unsigned short u){
  union { float f; unsigned int i; } x; x.i = ((unsigned int)u) << 16; return x.f;
}
__device__ __forceinline__ unsigned short f2bf(float f){
  union { float f; unsigned int i; } x; x.f = f;
  unsigned int r = x.i + 0x7FFFu + ((x.i >> 16) & 1u);
  return (unsigned short)(r >> 16);
}

#define MFMA16(a,b,c) __builtin_amdgcn_mfma_f32_16x16x32_bf16(a,b,c,0,0,0)

__device__ __forceinline__ void gload_lds16(const void* g, void* l){
  __builtin_amdgcn_global_load_lds(
    (const __attribute__((address_space(1))) unsigned int*)g,
    (__attribute__((address_space(3))) unsigned int*)l, 16, 0, 0);
}

// ---------- f32 -> bf16 convert, 4 elems/thread ----------
__global__ __launch_bounds__(256) void k_cvt(const float4* __restrict__ in,
                                             ushort4* __restrict__ out){
  int i = blockIdx.x*256 + threadIdx.x;
  float4 v = in[i];
  ushort4 o;
  o.x = f2bf(v.x); o.y = f2bf(v.y); o.z = f2bf(v.z); o.w = f2bf(v.w);
  out[i] = o;
}

// ---------- weight transpose+convert: W[K][N] f32 -> Wt[N][K] bf16 ----------
__global__ __launch_bounds__(256) void k_wtrans(const float* __restrict__ W,
                                                unsigned short* __restrict__ Wt,
                                                int K, int N){
  __shared__ float t[64][65];
  int n0 = blockIdx.x*64, k0 = blockIdx.y*64;
  int tid = threadIdx.x;
  int cr = tid & 63, rr = tid >> 6;
  #pragma unroll
  for (int i=0;i<16;++i){
    int r = i*4 + rr;
    t[cr][r] = W[(size_t)(k0 + r)*N + n0 + cr];
  }
  __syncthreads();
  int n = tid >> 2, kc = (tid & 3)*16;
  __align__(16) unsigned short tmp[16];
  #pragma unroll
  for (int j=0;j<16;++j) tmp[j] = f2bf(t[n][kc+j]);
  uint4* dst = reinterpret_cast<uint4*>(&Wt[(size_t)(n0+n)*K + k0 + kc]);
  dst[0] = *reinterpret_cast<uint4*>(&tmp[0]);
  dst[1] = *reinterpret_cast<uint4*>(&tmp[8]);
}

// ---------- bf16 GEMM: A[M][K] @ Bt[N][K]^T -> C[M][N] ----------
// 128x128 tile, BK=64, global_load_lds(16B) staging, XOR-swizzled LDS reads.
template<int OUTF32>
__global__ __launch_bounds__(256) void k_gemm(const unsigned short* __restrict__ A,
                                              const unsigned short* __restrict__ Bt,
                                              void* __restrict__ Cv,
                                              const float* __restrict__ bias,
                                              int N, int K){
  __shared__ __align__(16) unsigned short As[128*64];
  __shared__ __align__(16) unsigned short Bs[128*64];
  const int tid = threadIdx.x;
  const int w = tid >> 6, l = tid & 63;
  const int m0 = blockIdx.y*128, n0 = blockIdx.x*128;
  const int wr = (w >> 1)*64, wc = (w & 1)*64;
  const int lr8 = l >> 3;              // 0..7: row within 8-row segment
  const int lcs = ((l & 7) ^ lr8)*8;   // pre-swizzled source col (elements)
  const int lane_r = l & 15, lane_g = l >> 4;
  f32x4 acc[4][4] = {};
  for (int kt = 0; kt < K; kt += 64){
    #pragma unroll
    for (int i=0;i<4;++i){
      int seg = w*4 + i;
      int row = seg*8 + lr8;
      gload_lds16(&A[(size_t)(m0+row)*K + kt + lcs], &As[seg*512]);
      gload_lds16(&Bt[(size_t)(n0+row)*K + kt + lcs], &Bs[seg*512]);
    }
    __syncthreads();
    #pragma unroll
    for (int kk=0;kk<2;++kk){
      bf16x8 af[4], bfr[4];
      #pragma unroll
      for (int mt=0;mt<4;++mt){
        int row = wr + mt*16 + lane_r;
        int off = row*128 + kk*64 + lane_g*16;
        off ^= (row & 7) << 4;
        af[mt] = *reinterpret_cast<const bf16x8*>((const char*)As + off);
      }
      #pragma unroll
      for (int nt=0;nt<4;++nt){
        int row = wc + nt*16 + lane_r;
        int off = row*128 + kk*64 + lane_g*16;
        off ^= (row & 7) << 4;
        bfr[nt] = *reinterpret_cast<const bf16x8*>((const char*)Bs + off);
      }
      #pragma unroll
      for (int mt=0;mt<4;++mt)
        #pragma unroll
        for (int nt=0;nt<4;++nt)
          acc[mt][nt] = MFMA16(af[mt], bfr[nt], acc[mt][nt]);
    }
    __syncthreads();
  }
  #pragma unroll
  for (int mt=0;mt<4;++mt)
    #pragma unroll
    for (int nt=0;nt<4;++nt){
      int gn = n0 + wc + nt*16 + lane_r;
      #pragma unroll
      for (int r=0;r<4;++r){
        int gm = m0 + wr + mt*16 + lane_g*4 + r;
        float v = acc[mt][nt][r];
        if (OUTF32)
          ((float*)Cv)[(size_t)gm*N + gn] = v + bias[gn];
        else
          ((unsigned short*)Cv)[(size_t)gm*N + gn] = f2bf(v);
      }
    }
}

// ---------- per-column (sequence-axis) sum / sumsq via atomics ----------
__global__ __launch_bounds__(256) void k_colstats(const unsigned short* __restrict__ X,
                                                  float* __restrict__ stats,
                                                  int rowW, int statoff){
  int c = blockIdx.x*512 + threadIdx.x*2;
  int b = blockIdx.z;
  int r0 = blockIdx.y*128;
  const unsigned short* p = X + (size_t)(b*NS + r0)*rowW + c;
  float s0=0.f,s1=0.f,q0=0.f,q1=0.f;
  for (int r=0;r<128;++r){
    unsigned int v = *reinterpret_cast<const unsigned int*>(p);
    float x0 = bf2f((unsigned short)(v & 0xffffu));
    float x1 = bf2f((unsigned short)(v >> 16));
    s0 += x0; q0 += x0*x0; s1 += x1; q1 += x1*x1;
    p += rowW;
  }
  float* sp = stats + (size_t)(b*3*ND + statoff + c)*2;
  atomicAdd(sp+0, s0); atomicAdd(sp+1, q0);
  atomicAdd(sp+2, s1); atomicAdd(sp+3, q1);
}

__global__ __launch_bounds__(256) void k_statsfinal(const float* __restrict__ stats,
                                                    float2* __restrict__ sf){
  int i = blockIdx.x*256 + threadIdx.x;
  float sum = stats[i*2], sq = stats[i*2+1];
  float mean = sum * (1.0f/NS);
  float var = fmaxf(sq * (1.0f/NS) - mean*mean, 0.0f);
  float inv = 1.0f / (sqrtf(var) + EPSN);
  sf[i] = make_float2(inv, -mean*inv);
}

// ---------- in-place normalize of a [rows][rowW] bf16 buffer, cols [0,1024) ----------
__global__ __launch_bounds__(256) void k_norm(unsigned short* __restrict__ X,
                                              const float2* __restrict__ sf,
                                              int rowW, int statoff){
  int idx = blockIdx.x*256 + threadIdx.x;
  int row = idx >> 8;
  int c = (idx & 255)*4;
  int b = row >> 11;  // row / NS
  unsigned short* p = X + (size_t)row*rowW + c;
  uint2 v = *reinterpret_cast<const uint2*>(p);
  const float2* s = sf + (size_t)b*3*ND + statoff + c;
  float2 s0=s[0], s1=s[1], s2=s[2], s3=s[3];
  unsigned int lo = (unsigned int)f2bf(bf2f((unsigned short)(v.x & 0xffffu))*s0.x + s0.y)
                  | ((unsigned int)f2bf(bf2f((unsigned short)(v.x >> 16))*s1.x + s1.y) << 16);
  unsigned int hi = (unsigned int)f2bf(bf2f((unsigned short)(v.y & 0xffffu))*s2.x + s2.y)
                  | ((unsigned int)f2bf(bf2f((unsigned short)(v.y >> 16))*s3.x + s3.y) << 16);
  *reinterpret_cast<uint2*>(p) = make_uint2(lo, hi);
}

// ---------- V-half normalize + transpose: kv[..,D+h*64+c] -> vt[B,H,HD,S] ----------
__global__ __launch_bounds__(256) void k_vtrans(const unsigned short* __restrict__ kv,
                                                unsigned short* __restrict__ vt,
                                                const float2* __restrict__ sf){
  __shared__ unsigned short t[64][72];
  int s0 = blockIdx.x*64, h = blockIdx.y, b = blockIdx.z;
  int tid = threadIdx.x;
  int rr = tid >> 4;
  int cc = (tid & 15)*4;
  const float2* sp = sf + (size_t)b*3*ND + 2*ND + h*64 + cc;
  float2 f0=sp[0], f1=sp[1], f2v=sp[2], f3=sp[3];
  #pragma unroll
  for (int i=0;i<4;++i){
    int r = i*16 + rr;
    const unsigned short* p = kv + (size_t)(b*NS + s0 + r)*2048 + ND + h*64 + cc;
    uint2 v = *reinterpret_cast<const uint2*>(p);
    t[cc+0][r] = f2bf(bf2f((unsigned short)(v.x & 0xffffu))*f0.x + f0.y);
    t[cc+1][r] = f2bf(bf2f((unsigned short)(v.x >> 16))*f1.x + f1.y);
    t[cc+2][r] = f2bf(bf2f((unsigned short)(v.y & 0xffffu))*f2v.x + f2v.y);
    t[cc+3][r] = f2bf(bf2f((unsigned short)(v.y >> 16))*f3.x + f3.y);
  }
  __syncthreads();
  int hd = tid >> 2, scn = (tid & 3)*16;
  __align__(16) unsigned short tmp[16];
  #pragma unroll
  for (int j=0;j<16;++j) tmp[j] = t[hd][scn+j];
  uint4* dst = reinterpret_cast<uint4*>(&vt[((size_t)(b*NH + h)*64 + hd)*NS + s0 + scn]);
  dst[0] = *reinterpret_cast<uint4*>(&tmp[0]);
  dst[1] = *reinterpret_cast<uint4*>(&tmp[8]);
}

// ---------- causal flash attention, 4 waves x 16 q-rows, KVBLK=64 ----------
__global__ __launch_bounds__(256) void k_attn(const unsigned short* __restrict__ qn,
                                              const unsigned short* __restrict__ kn,
                                              const unsigned short* __restrict__ vt,
                                              unsigned short* __restrict__ heads){
  __shared__ __align__(16) unsigned short plds[4][16][72];
  const int qt = blockIdx.x, h = blockIdx.y, b = blockIdx.z;
  const int tid = threadIdx.x, w = tid >> 6, l = tid & 63;
  const int lr = l & 15, lg = l >> 4;
  const int q0 = qt*64 + w*16;
  const unsigned short* qp = qn + (size_t)(b*NS + q0 + lr)*ND + h*64 + lg*8;
  bf16x8 qa0 = *reinterpret_cast<const bf16x8*>(qp);
  bf16x8 qa1 = *reinterpret_cast<const bf16x8*>(qp + 32);
  float m[4], ls[4];
  f32x4 o[4] = {};
  #pragma unroll
  for (int r=0;r<4;++r){ m[r] = -1e30f; ls[r] = 0.f; }
  const unsigned short* kbase = kn + (size_t)b*NS*2048 + h*64 + lg*8;
  const unsigned short* vbase = vt + ((size_t)(b*NH + h)*64 + lr)*NS + lg*8;
  for (int kt = 0; kt <= qt; ++kt){
    const int k0 = kt*64;
    f32x4 sc[4];
    #pragma unroll
    for (int kc=0;kc<4;++kc){
      const unsigned short* kp = kbase + (size_t)(k0 + kc*16 + lr)*2048;
      bf16x8 kb0 = *reinterpret_cast<const bf16x8*>(kp);
      bf16x8 kb1 = *reinterpret_cast<const bf16x8*>(kp + 32);
      f32x4 a = {};
      a = MFMA16(qa0, kb0, a);
      a = MFMA16(qa1, kb1, a);
      sc[kc] = a;
    }
    float rm[4];
    #pragma unroll
    for (int r=0;r<4;++r){
      const int qrow = q0 + lg*4 + r;
      float mx = -1e30f;
      #pragma unroll
      for (int kc=0;kc<4;++kc){
        const int kcol = k0 + kc*16 + lr;
        float sv = sc[kc][r]*0.125f;
        sv = (kcol > qrow) ? -1e30f : sv;
        sc[kc][r] = sv;
        mx = fmaxf(mx, sv);
      }
      rm[r] = mx;
    }
    #pragma unroll
    for (int d=1; d<16; d<<=1){
      #pragma unroll
      for (int r=0;r<4;++r) rm[r] = fmaxf(rm[r], __shfl_xor(rm[r], d, 64));
    }
    float rs[4];
    #pragma unroll
    for (int r=0;r<4;++r){
      float nm = fmaxf(m[r], rm[r]);
      float sfac = __expf(m[r] - nm);
      m[r] = nm;
      ls[r] *= sfac;
      #pragma unroll
      for (int dt=0;dt<4;++dt) o[dt][r] *= sfac;
      float sum = 0.f;
      #pragma unroll
      for (int kc=0;kc<4;++kc){
        float pv = __expf(sc[kc][r] - nm);
        sc[kc][r] = pv;
        sum += pv;
      }
      rs[r] = sum;
    }
    #pragma unroll
    for (int d=1; d<16; d<<=1){
      #pragma unroll
      for (int r=0;r<4;++r) rs[r] += __shfl_xor(rs[r], d, 64);
    }
    #pragma unroll
    for (int r=0;r<4;++r) ls[r] += rs[r];
    #pragma unroll
    for (int kc=0;kc<4;++kc)
      #pragma unroll
      for (int r=0;r<4;++r)
        plds[w][lg*4+r][kc*16+lr] = f2bf(sc[kc][r]);
    __syncthreads();
    bf16x8 pf0 = *reinterpret_cast<const bf16x8*>(&plds[w][lr][lg*8]);
    bf16x8 pf1 = *reinterpret_cast<const bf16x8*>(&plds[w][lr][32 + lg*8]);
    #pragma unroll
    for (int dt=0;dt<4;++dt){
      const unsigned short* vp = vbase + (size_t)dt*16*NS + k0;
      bf16x8 vb0 = *reinterpret_cast<const bf16x8*>(vp);
      bf16x8 vb1 = *reinterpret_cast<const bf16x8*>(vp + 32);
      o[dt] = MFMA16(pf0, vb0, o[dt]);
      o[dt] = MFMA16(pf1, vb1, o[dt]);
    }
    __syncthreads();
  }
  #pragma unroll
  for (int r=0;r<4;++r) ls[r] = 1.0f / ls[r];
  #pragma unroll
  for (int dt=0;dt<4;++dt)
    #pragma unroll
    for (int r=0;r<4;++r){
      int gq = q0 + lg*4 + r;
      heads[(size_t)(b*NS + gq)*ND + h*64 + dt*16 + lr] = f2bf(o[dt][r]*ls[r]);
    }
}

extern "C" void kernel_launch(void* const* d_in, const int* in_sizes, int n_in,
                              void* d_out, int out_size, void* d_ws, size_t ws_size,
                              hipStream_t stream){
  (void)in_sizes; (void)n_in; (void)out_size; (void)ws_size;
  const float* query = (const float*)d_in[0];
  const float* value = (const float*)d_in[1];
  // d_in[2] = mask: provably causal per setup -> hardcoded in k_attn
  const float* Wq  = (const float*)d_in[3];
  // d_in[4]=bq, d_in[6]=bkv: cancel under column-mean subtraction -> skipped
  const float* Wkv = (const float*)d_in[5];
  const float* Wo  = (const float*)d_in[7];
  const float* bo  = (const float*)d_in[8];

  char* ws = (char*)d_ws;
  unsigned short* qx    = (unsigned short*)(ws + 0);          // 16MB (aliased: vt later)
  unsigned short* vx    = (unsigned short*)(ws + 16777216);   // 16MB (aliased: heads later)
  unsigned short* wqt   = (unsigned short*)(ws + 33554432);   // 2MB
  unsigned short* wkvt  = (unsigned short*)(ws + 35651584);   // 4MB
  unsigned short* wot   = (unsigned short*)(ws + 39845888);   // 2MB
  unsigned short* qbuf  = (unsigned short*)(ws + 41943040);   // 16MB
  unsigned short* kvbuf = (unsigned short*)(ws + 58720256);   // 32MB
  float*          stats = (float*)(ws + 92274688);            // 96KB
  float2*         sfin  = (float2*)(ws + 92372992);           // 96KB
  unsigned short* vtb   = qx;   // qx dead after first GEMM
  unsigned short* heads = vx;   // vx dead after second GEMM

  hipMemsetAsync(stats, 0, NB*3*ND*2*sizeof(float), stream);
  k_cvt<<<8192, 256, 0, stream>>>((const float4*)query, (ushort4*)qx);
  k_cvt<<<8192, 256, 0, stream>>>((const float4*)value, (ushort4*)vx);
  k_wtrans<<<dim3(16,16), 256, 0, stream>>>(Wq, wqt, 1024, 1024);
  k_wtrans<<<dim3(32,16), 256, 0, stream>>>(Wkv, wkvt, 1024, 2048);
  k_wtrans<<<dim3(16,16), 256, 0, stream>>>(Wo, wot, 1024, 1024);
  k_gemm<0><<<dim3(8,64), 256, 0, stream>>>(qx, wqt, qbuf, nullptr, 1024, 1024);
  k_gemm<0><<<dim3(16,64), 256, 0, stream>>>(vx, wkvt, kvbuf, nullptr, 2048, 1024);
  k_colstats<<<dim3(2,16,4), 256, 0, stream>>>(qbuf, stats, 1024, 0);
  k_colstats<<<dim3(4,16,4), 256, 0, stream>>>(kvbuf, stats, 2048, 1024);
  k_statsfinal<<<48, 256, 0, stream>>>(stats, sfin);
  k_norm<<<8192, 256, 0, stream>>>(qbuf, sfin, 1024, 0);
  k_norm<<<8192, 256, 0, stream>>>(kvbuf, sfin, 2048, 1024);
  k_vtrans<<<dim3(32,16,4), 256, 0, stream>>>(kvbuf, vtb, sfin);
  k_attn<<<dim3(32,16,4), 256, 0, stream>>>(qbuf, kvbuf, vtb, heads);
  k_gemm<1><<<dim3(8,64), 256, 0, stream>>>(heads, wot, d_out, bo, 1024, 1024);
}

// Round 2
// 460.325 us; speedup vs baseline: 1.6978x; 1.6978x over previous
//
#include <hip/hip_runtime.h>
#include <stdint.h>

#define NB 4
#define NS 2048
#define ND 1024
#define NH 16
#define EPSN 0.01f

typedef short bf16x8 __attribute__((ext_vector_type(8)));
typedef float f32x4 __attribute__((ext_vector_type(4)));

__device__ __forceinline__ float bf2f(unsigned short u){
  union { float f; unsigned int i; } x; x.i = ((unsigned int)u) << 16; return x.f;
}
__device__ __forceinline__ unsigned short f2bf(float f){
  union { float f; unsigned int i; } x; x.f = f;
  unsigned int r = x.i + 0x7FFFu + ((x.i >> 16) & 1u);
  return (unsigned short)(r >> 16);
}

#define MFMA16(a,b,c) __builtin_amdgcn_mfma_f32_16x16x32_bf16(a,b,c,0,0,0)

__device__ __forceinline__ void gload_lds16(const void* g, void* l){
  __builtin_amdgcn_global_load_lds(
    (const __attribute__((address_space(1))) unsigned int*)g,
    (__attribute__((address_space(3))) unsigned int*)l, 16, 0, 0);
}

// ---------- f32 -> bf16 convert, 4 elems/thread ----------
__global__ __launch_bounds__(256) void k_cvt(const float4* __restrict__ in,
                                             ushort4* __restrict__ out){
  int i = blockIdx.x*256 + threadIdx.x;
  float4 v = in[i];
  ushort4 o;
  o.x = f2bf(v.x); o.y = f2bf(v.y); o.z = f2bf(v.z); o.w = f2bf(v.w);
  out[i] = o;
}

// ---------- weight transpose+convert: W[K][N] f32 -> Wt[N][K] bf16 ----------
__global__ __launch_bounds__(256) void k_wtrans(const float* __restrict__ W,
                                                unsigned short* __restrict__ Wt,
                                                int K, int N){
  __shared__ float t[64][65];
  int n0 = blockIdx.x*64, k0 = blockIdx.y*64;
  int tid = threadIdx.x;
  int cr = tid & 63, rr = tid >> 6;
  #pragma unroll
  for (int i=0;i<16;++i){
    int r = i*4 + rr;
    t[cr][r] = W[(size_t)(k0 + r)*N + n0 + cr];
  }
  __syncthreads();
  int n = tid >> 2, kc = (tid & 3)*16;
  __align__(16) unsigned short tmp[16];
  #pragma unroll
  for (int j=0;j<16;++j) tmp[j] = f2bf(t[n][kc+j]);
  uint4* dst = reinterpret_cast<uint4*>(&Wt[(size_t)(n0+n)*K + k0 + kc]);
  dst[0] = *reinterpret_cast<uint4*>(&tmp[0]);
  dst[1] = *reinterpret_cast<uint4*>(&tmp[8]);
}

// ---------- bf16 GEMM: A[M][K] @ Bt[N][K]^T -> C[M][N] ----------
template<int OUTF32>
__global__ __launch_bounds__(256) void k_gemm(const unsigned short* __restrict__ A,
                                              const unsigned short* __restrict__ Bt,
                                              void* __restrict__ Cv,
                                              const float* __restrict__ bias,
                                              int N, int K){
  __shared__ __align__(16) unsigned short As[128*64];
  __shared__ __align__(16) unsigned short Bs[128*64];
  const int tid = threadIdx.x;
  const int w = tid >> 6, l = tid & 63;
  const int m0 = blockIdx.y*128, n0 = blockIdx.x*128;
  const int wr = (w >> 1)*64, wc = (w & 1)*64;
  const int lr8 = l >> 3;
  const int lcs = ((l & 7) ^ lr8)*8;
  const int lane_r = l & 15, lane_g = l >> 4;
  f32x4 acc[4][4] = {};
  for (int kt = 0; kt < K; kt += 64){
    #pragma unroll
    for (int i=0;i<4;++i){
      int seg = w*4 + i;
      int row = seg*8 + lr8;
      gload_lds16(&A[(size_t)(m0+row)*K + kt + lcs], &As[seg*512]);
      gload_lds16(&Bt[(size_t)(n0+row)*K + kt + lcs], &Bs[seg*512]);
    }
    __syncthreads();
    #pragma unroll
    for (int kk=0;kk<2;++kk){
      bf16x8 af[4], bfr[4];
      #pragma unroll
      for (int mt=0;mt<4;++mt){
        int row = wr + mt*16 + lane_r;
        int off = row*128 + kk*64 + lane_g*16;
        off ^= (row & 7) << 4;
        af[mt] = *reinterpret_cast<const bf16x8*>((const char*)As + off);
      }
      #pragma unroll
      for (int nt=0;nt<4;++nt){
        int row = wc + nt*16 + lane_r;
        int off = row*128 + kk*64 + lane_g*16;
        off ^= (row & 7) << 4;
        bfr[nt] = *reinterpret_cast<const bf16x8*>((const char*)Bs + off);
      }
      #pragma unroll
      for (int mt=0;mt<4;++mt)
        #pragma unroll
        for (int nt=0;nt<4;++nt)
          acc[mt][nt] = MFMA16(af[mt], bfr[nt], acc[mt][nt]);
    }
    __syncthreads();
  }
  #pragma unroll
  for (int mt=0;mt<4;++mt)
    #pragma unroll
    for (int nt=0;nt<4;++nt){
      int gn = n0 + wc + nt*16 + lane_r;
      #pragma unroll
      for (int r=0;r<4;++r){
        int gm = m0 + wr + mt*16 + lane_g*4 + r;
        float v = acc[mt][nt][r];
        if (OUTF32)
          ((float*)Cv)[(size_t)gm*N + gn] = v + bias[gn];
        else
          ((unsigned short*)Cv)[(size_t)gm*N + gn] = f2bf(v);
      }
    }
}

// ---------- per-column (sequence-axis) sum / sumsq via atomics ----------
__global__ __launch_bounds__(256) void k_colstats(const unsigned short* __restrict__ X,
                                                  float* __restrict__ stats,
                                                  int rowW, int statoff){
  int c = blockIdx.x*512 + threadIdx.x*2;
  int b = blockIdx.z;
  int r0 = blockIdx.y*128;
  const unsigned short* p = X + (size_t)(b*NS + r0)*rowW + c;
  float s0=0.f,s1=0.f,q0=0.f,q1=0.f;
  for (int r=0;r<128;++r){
    unsigned int v = *reinterpret_cast<const unsigned int*>(p);
    float x0 = bf2f((unsigned short)(v & 0xffffu));
    float x1 = bf2f((unsigned short)(v >> 16));
    s0 += x0; q0 += x0*x0; s1 += x1; q1 += x1*x1;
    p += rowW;
  }
  float* sp = stats + (size_t)(b*3*ND + statoff + c)*2;
  atomicAdd(sp+0, s0); atomicAdd(sp+1, q0);
  atomicAdd(sp+2, s1); atomicAdd(sp+3, q1);
}

// q columns get the attention scale (1/8) and log2e folded in, so exp becomes
// a bare exp2 and the per-score scale multiply disappears.
__global__ __launch_bounds__(256) void k_statsfinal(const float* __restrict__ stats,
                                                    float2* __restrict__ sf){
  int i = blockIdx.x*256 + threadIdx.x;
  float sum = stats[i*2], sq = stats[i*2+1];
  float mean = sum * (1.0f/NS);
  float var = fmaxf(sq * (1.0f/NS) - mean*mean, 0.0f);
  float inv = 1.0f / (sqrtf(var) + EPSN);
  int col = i % (3*ND);
  if (col < ND) inv *= 0.125f * 1.44269504088896340736f;
  sf[i] = make_float2(inv, -mean*inv);
}

// ---------- in-place normalize of a [rows][rowW] bf16 buffer, cols [0,1024) ----------
__global__ __launch_bounds__(256) void k_norm(unsigned short* __restrict__ X,
                                              const float2* __restrict__ sf,
                                              int rowW, int statoff){
  int idx = blockIdx.x*256 + threadIdx.x;
  int row = idx >> 8;
  int c = (idx & 255)*4;
  int b = row >> 11;
  unsigned short* p = X + (size_t)row*rowW + c;
  uint2 v = *reinterpret_cast<const uint2*>(p);
  const float2* s = sf + (size_t)b*3*ND + statoff + c;
  float2 s0=s[0], s1=s[1], s2=s[2], s3=s[3];
  unsigned int lo = (unsigned int)f2bf(bf2f((unsigned short)(v.x & 0xffffu))*s0.x + s0.y)
                  | ((unsigned int)f2bf(bf2f((unsigned short)(v.x >> 16))*s1.x + s1.y) << 16);
  unsigned int hi = (unsigned int)f2bf(bf2f((unsigned short)(v.y & 0xffffu))*s2.x + s2.y)
                  | ((unsigned int)f2bf(bf2f((unsigned short)(v.y >> 16))*s3.x + s3.y) << 16);
  *reinterpret_cast<uint2*>(p) = make_uint2(lo, hi);
}

// ---------- V-half normalize + transpose: kv[..,D+h*64+c] -> vt[B,H,HD,S] ----------
__global__ __launch_bounds__(256) void k_vtrans(const unsigned short* __restrict__ kv,
                                                unsigned short* __restrict__ vt,
                                                const float2* __restrict__ sf){
  __shared__ unsigned short t[64][72];
  int s0 = blockIdx.x*64, h = blockIdx.y, b = blockIdx.z;
  int tid = threadIdx.x;
  int rr = tid >> 4;
  int cc = (tid & 15)*4;
  const float2* sp = sf + (size_t)b*3*ND + 2*ND + h*64 + cc;
  float2 f0=sp[0], f1=sp[1], f2v=sp[2], f3=sp[3];
  #pragma unroll
  for (int i=0;i<4;++i){
    int r = i*16 + rr;
    const unsigned short* p = kv + (size_t)(b*NS + s0 + r)*2048 + ND + h*64 + cc;
    uint2 v = *reinterpret_cast<const uint2*>(p);
    t[cc+0][r] = f2bf(bf2f((unsigned short)(v.x & 0xffffu))*f0.x + f0.y);
    t[cc+1][r] = f2bf(bf2f((unsigned short)(v.x >> 16))*f1.x + f1.y);
    t[cc+2][r] = f2bf(bf2f((unsigned short)(v.y & 0xffffu))*f2v.x + f2v.y);
    t[cc+3][r] = f2bf(bf2f((unsigned short)(v.y >> 16))*f3.x + f3.y);
  }
  __syncthreads();
  int hd = tid >> 2, scn = (tid & 3)*16;
  __align__(16) unsigned short tmp[16];
  #pragma unroll
  for (int j=0;j<16;++j) tmp[j] = t[hd][scn+j];
  uint4* dst = reinterpret_cast<uint4*>(&vt[((size_t)(b*NH + h)*64 + hd)*NS + s0 + scn]);
  dst[0] = *reinterpret_cast<uint4*>(&tmp[0]);
  dst[1] = *reinterpret_cast<uint4*>(&tmp[8]);
}

// ---------- causal attention, 4 waves x 32 q-rows, KVBLK=64, no barriers ----------
// Swapped MFMA operands: QK^T computed as S^T = K*Q^T (lane's 4 regs = 4
// consecutive k for ONE q=lane&15 -> b64 P writes, lane-local denominator),
// PV computed as O^T = V^T*P^T (lane's 4 regs = 4 consecutive d -> b64 stores).
// No online max: scores are bounded (normalized inputs), P = exp2(prescaled s).
__global__ __launch_bounds__(256) void k_attn(const unsigned short* __restrict__ qn,
                                              const unsigned short* __restrict__ kn,
                                              const unsigned short* __restrict__ vt,
                                              unsigned short* __restrict__ heads){
  __shared__ __align__(16) unsigned short plds[4][32][72];
  const int bid = blockIdx.x;
  // XCD-chunked swizzle: all q-tiles of one (b,h) land on one XCD's L2.
  const int nb = (bid & 7)*128 + (bid >> 3);
  // mix qb so no CU slot pattern sees only heavy diagonal blocks
  const int qb = ((nb & 15) + ((nb >> 4) & 3)) & 15;
  const int hb = nb >> 4;
  const int h = hb & 15, b = hb >> 4;
  const int tid = threadIdx.x, w = tid >> 6, l = tid & 63;
  const int lr = l & 15, lg = l >> 4;
  const int q0 = qb*128 + w*32;

  const unsigned short* qp = qn + (size_t)(b*NS + q0 + lr)*ND + h*64 + lg*8;
  bf16x8 qa[2][2];
  qa[0][0] = *reinterpret_cast<const bf16x8*>(qp);
  qa[0][1] = *reinterpret_cast<const bf16x8*>(qp + 32);
  qa[1][0] = *reinterpret_cast<const bf16x8*>(qp + 16*ND);
  qa[1][1] = *reinterpret_cast<const bf16x8*>(qp + 16*ND + 32);

  f32x4 o[2][4] = {};
  float rs0 = 0.f, rs1 = 0.f;
  const unsigned short* kbase = kn + (size_t)b*NS*2048 + h*64 + lg*8;
  const unsigned short* vbase = vt + ((size_t)(b*NH + h)*64 + lr)*NS + lg*8;
  const int ktw = ((q0 + 31) >> 6) + 1;

  for (int kt = 0; kt < ktw; ++kt){
    const int k0 = kt*64;
    bf16x8 kb[4][2];
    #pragma unroll
    for (int kc=0;kc<4;++kc){
      const unsigned short* kp = kbase + (size_t)(k0 + kc*16 + lr)*2048;
      kb[kc][0] = *reinterpret_cast<const bf16x8*>(kp);
      kb[kc][1] = *reinterpret_cast<const bf16x8*>(kp + 32);
    }
    const bool nomask = (k0 + 63 <= q0);
    #pragma unroll
    for (int g=0; g<2; ++g){
      f32x4 sc[4];
      #pragma unroll
      for (int kc=0;kc<4;++kc){
        f32x4 a = {};
        a = MFMA16(kb[kc][0], qa[g][0], a);
        a = MFMA16(kb[kc][1], qa[g][1], a);
        sc[kc] = a;
      }
      const int qrow = q0 + g*16 + lr;
      float acc = 0.f;
      if (nomask){
        #pragma unroll
        for (int kc=0;kc<4;++kc)
          #pragma unroll
          for (int r=0;r<4;++r){
            float pv = exp2f(sc[kc][r]);
            sc[kc][r] = pv;
            acc += pv;
          }
      } else {
        #pragma unroll
        for (int kc=0;kc<4;++kc)
          #pragma unroll
          for (int r=0;r<4;++r){
            int kcol = k0 + kc*16 + lg*4 + r;
            float pv = (kcol <= qrow) ? exp2f(sc[kc][r]) : 0.f;
            sc[kc][r] = pv;
            acc += pv;
          }
      }
      if (g) rs1 += acc; else rs0 += acc;
      #pragma unroll
      for (int kc=0;kc<4;++kc){
        ushort4 pk;
        pk.x = f2bf(sc[kc][0]); pk.y = f2bf(sc[kc][1]);
        pk.z = f2bf(sc[kc][2]); pk.w = f2bf(sc[kc][3]);
        *reinterpret_cast<ushort4*>(&plds[w][g*16 + lr][kc*16 + lg*4]) = pk;
      }
    }
    // wave-private LDS write->read ordering (no block barrier needed)
    asm volatile("s_waitcnt lgkmcnt(0)" ::: "memory");
    __builtin_amdgcn_sched_barrier(0);
    bf16x8 pf[2][2];
    #pragma unroll
    for (int g=0; g<2; ++g){
      pf[g][0] = *reinterpret_cast<const bf16x8*>(&plds[w][g*16 + lr][lg*8]);
      pf[g][1] = *reinterpret_cast<const bf16x8*>(&plds[w][g*16 + lr][32 + lg*8]);
    }
    #pragma unroll
    for (int dt=0; dt<4; ++dt){
      const unsigned short* vp = vbase + (size_t)dt*16*NS + k0;
      bf16x8 vb0 = *reinterpret_cast<const bf16x8*>(vp);
      bf16x8 vb1 = *reinterpret_cast<const bf16x8*>(vp + 32);
      o[0][dt] = MFMA16(vb0, pf[0][0], o[0][dt]);
      o[0][dt] = MFMA16(vb1, pf[0][1], o[0][dt]);
      o[1][dt] = MFMA16(vb0, pf[1][0], o[1][dt]);
      o[1][dt] = MFMA16(vb1, pf[1][1], o[1][dt]);
    }
  }

  rs0 += __shfl_xor(rs0, 16, 64); rs0 += __shfl_xor(rs0, 32, 64);
  rs1 += __shfl_xor(rs1, 16, 64); rs1 += __shfl_xor(rs1, 32, 64);
  float inv0 = 1.0f / rs0, inv1 = 1.0f / rs1;
  #pragma unroll
  for (int g=0; g<2; ++g){
    float inv = g ? inv1 : inv0;
    #pragma unroll
    for (int dt=0; dt<4; ++dt){
      ushort4 ov;
      ov.x = f2bf(o[g][dt][0]*inv); ov.y = f2bf(o[g][dt][1]*inv);
      ov.z = f2bf(o[g][dt][2]*inv); ov.w = f2bf(o[g][dt][3]*inv);
      *reinterpret_cast<ushort4*>(
        &heads[(size_t)(b*NS + q0 + g*16 + lr)*ND + h*64 + dt*16 + lg*4]) = ov;
    }
  }
}

extern "C" void kernel_launch(void* const* d_in, const int* in_sizes, int n_in,
                              void* d_out, int out_size, void* d_ws, size_t ws_size,
                              hipStream_t stream){
  (void)in_sizes; (void)n_in; (void)out_size; (void)ws_size;
  const float* query = (const float*)d_in[0];
  const float* value = (const float*)d_in[1];
  const float* Wq  = (const float*)d_in[3];
  const float* Wkv = (const float*)d_in[5];
  const float* Wo  = (const float*)d_in[7];
  const float* bo  = (const float*)d_in[8];

  char* ws = (char*)d_ws;
  unsigned short* qx    = (unsigned short*)(ws + 0);          // 16MB (aliased: vt later)
  unsigned short* vx    = (unsigned short*)(ws + 16777216);   // 16MB (aliased: heads later)
  unsigned short* wqt   = (unsigned short*)(ws + 33554432);   // 2MB
  unsigned short* wkvt  = (unsigned short*)(ws + 35651584);   // 4MB
  unsigned short* wot   = (unsigned short*)(ws + 39845888);   // 2MB
  unsigned short* qbuf  = (unsigned short*)(ws + 41943040);   // 16MB
  unsigned short* kvbuf = (unsigned short*)(ws + 58720256);   // 32MB
  float*          stats = (float*)(ws + 92274688);            // 96KB
  float2*         sfin  = (float2*)(ws + 92372992);           // 96KB
  unsigned short* vtb   = qx;
  unsigned short* heads = vx;

  hipMemsetAsync(stats, 0, NB*3*ND*2*sizeof(float), stream);
  k_cvt<<<8192, 256, 0, stream>>>((const float4*)query, (ushort4*)qx);
  k_cvt<<<8192, 256, 0, stream>>>((const float4*)value, (ushort4*)vx);
  k_wtrans<<<dim3(16,16), 256, 0, stream>>>(Wq, wqt, 1024, 1024);
  k_wtrans<<<dim3(32,16), 256, 0, stream>>>(Wkv, wkvt, 1024, 2048);
  k_wtrans<<<dim3(16,16), 256, 0, stream>>>(Wo, wot, 1024, 1024);
  k_gemm<0><<<dim3(8,64), 256, 0, stream>>>(qx, wqt, qbuf, nullptr, 1024, 1024);
  k_gemm<0><<<dim3(16,64), 256, 0, stream>>>(vx, wkvt, kvbuf, nullptr, 2048, 1024);
  k_colstats<<<dim3(2,16,4), 256, 0, stream>>>(qbuf, stats, 1024, 0);
  k_colstats<<<dim3(4,16,4), 256, 0, stream>>>(kvbuf, stats, 2048, 1024);
  k_statsfinal<<<48, 256, 0, stream>>>(stats, sfin);
  k_norm<<<8192, 256, 0, stream>>>(qbuf, sfin, 1024, 0);
  k_norm<<<8192, 256, 0, stream>>>(kvbuf, sfin, 2048, 1024);
  k_vtrans<<<dim3(32,16,4), 256, 0, stream>>>(kvbuf, vtb, sfin);
  k_attn<<<1024, 256, 0, stream>>>(qbuf, kvbuf, vtb, heads);
  k_gemm<1><<<dim3(8,64), 256, 0, stream>>>(heads, wot, d_out, bo, 1024, 1024);
}

// Round 3
// 382.999 us; speedup vs baseline: 2.0405x; 1.2019x over previous
//
#include <hip/hip_runtime.h>
#include <stdint.h>

#define NB 4
#define NS 2048
#define ND 1024
#define NH 16
#define EPSN 0.01f

typedef short bf16x8 __attribute__((ext_vector_type(8)));
typedef float f32x4 __attribute__((ext_vector_type(4)));

__device__ __forceinline__ float bf2f(unsigned short u){
  union { float f; unsigned int i; } x; x.i = ((unsigned int)u) << 16; return x.f;
}
__device__ __forceinline__ unsigned short f2bf(float f){
  union { float f; unsigned int i; } x; x.f = f;
  unsigned int r = x.i + 0x7FFFu + ((x.i >> 16) & 1u);
  return (unsigned short)(r >> 16);
}
// packed f32->bf16 RNE: D.lo = bf16(a), D.hi = bf16(b)
__device__ __forceinline__ unsigned int cvtpk(float a, float b){
  unsigned int r;
  asm("v_cvt_pk_bf16_f32 %0, %1, %2" : "=v"(r) : "v"(a), "v"(b));
  return r;
}

#define MFMA16(a,b,c) __builtin_amdgcn_mfma_f32_16x16x32_bf16(a,b,c,0,0,0)

__device__ __forceinline__ void gload_lds16(const void* g, void* l){
  __builtin_amdgcn_global_load_lds(
    (const __attribute__((address_space(1))) unsigned int*)g,
    (__attribute__((address_space(3))) unsigned int*)l, 16, 0, 0);
}

// ---------- f32 -> bf16 convert, 4 elems/thread ----------
__global__ __launch_bounds__(256) void k_cvt(const float4* __restrict__ in,
                                             ushort4* __restrict__ out){
  int i = blockIdx.x*256 + threadIdx.x;
  float4 v = in[i];
  ushort4 o;
  o.x = f2bf(v.x); o.y = f2bf(v.y); o.z = f2bf(v.z); o.w = f2bf(v.w);
  out[i] = o;
}

// ---------- weight transpose+convert: W[K][N] f32 -> Wt[N][K] bf16 ----------
__global__ __launch_bounds__(256) void k_wtrans(const float* __restrict__ W,
                                                unsigned short* __restrict__ Wt,
                                                int K, int N){
  __shared__ float t[64][65];
  int n0 = blockIdx.x*64, k0 = blockIdx.y*64;
  int tid = threadIdx.x;
  int cr = tid & 63, rr = tid >> 6;
  #pragma unroll
  for (int i=0;i<16;++i){
    int r = i*4 + rr;
    t[cr][r] = W[(size_t)(k0 + r)*N + n0 + cr];
  }
  __syncthreads();
  int n = tid >> 2, kc = (tid & 3)*16;
  __align__(16) unsigned short tmp[16];
  #pragma unroll
  for (int j=0;j<16;++j) tmp[j] = f2bf(t[n][kc+j]);
  uint4* dst = reinterpret_cast<uint4*>(&Wt[(size_t)(n0+n)*K + k0 + kc]);
  dst[0] = *reinterpret_cast<uint4*>(&tmp[0]);
  dst[1] = *reinterpret_cast<uint4*>(&tmp[8]);
}

// ---------- bf16 GEMM: A[M][K] @ Bt[N][K]^T -> C[M][N] ----------
template<int OUTF32>
__global__ __launch_bounds__(256) void k_gemm(const unsigned short* __restrict__ A,
                                              const unsigned short* __restrict__ Bt,
                                              void* __restrict__ Cv,
                                              const float* __restrict__ bias,
                                              int N, int K){
  __shared__ __align__(16) unsigned short As[128*64];
  __shared__ __align__(16) unsigned short Bs[128*64];
  const int tid = threadIdx.x;
  const int w = tid >> 6, l = tid & 63;
  const int m0 = blockIdx.y*128, n0 = blockIdx.x*128;
  const int wr = (w >> 1)*64, wc = (w & 1)*64;
  const int lr8 = l >> 3;
  const int lcs = ((l & 7) ^ lr8)*8;
  const int lane_r = l & 15, lane_g = l >> 4;
  f32x4 acc[4][4] = {};
  for (int kt = 0; kt < K; kt += 64){
    #pragma unroll
    for (int i=0;i<4;++i){
      int seg = w*4 + i;
      int row = seg*8 + lr8;
      gload_lds16(&A[(size_t)(m0+row)*K + kt + lcs], &As[seg*512]);
      gload_lds16(&Bt[(size_t)(n0+row)*K + kt + lcs], &Bs[seg*512]);
    }
    __syncthreads();
    #pragma unroll
    for (int kk=0;kk<2;++kk){
      bf16x8 af[4], bfr[4];
      #pragma unroll
      for (int mt=0;mt<4;++mt){
        int row = wr + mt*16 + lane_r;
        int off = row*128 + kk*64 + lane_g*16;
        off ^= (row & 7) << 4;
        af[mt] = *reinterpret_cast<const bf16x8*>((const char*)As + off);
      }
      #pragma unroll
      for (int nt=0;nt<4;++nt){
        int row = wc + nt*16 + lane_r;
        int off = row*128 + kk*64 + lane_g*16;
        off ^= (row & 7) << 4;
        bfr[nt] = *reinterpret_cast<const bf16x8*>((const char*)Bs + off);
      }
      #pragma unroll
      for (int mt=0;mt<4;++mt)
        #pragma unroll
        for (int nt=0;nt<4;++nt)
          acc[mt][nt] = MFMA16(af[mt], bfr[nt], acc[mt][nt]);
    }
    __syncthreads();
  }
  #pragma unroll
  for (int mt=0;mt<4;++mt)
    #pragma unroll
    for (int nt=0;nt<4;++nt){
      int gn = n0 + wc + nt*16 + lane_r;
      #pragma unroll
      for (int r=0;r<4;++r){
        int gm = m0 + wr + mt*16 + lane_g*4 + r;
        float v = acc[mt][nt][r];
        if (OUTF32)
          ((float*)Cv)[(size_t)gm*N + gn] = v + bias[gn];
        else
          ((unsigned short*)Cv)[(size_t)gm*N + gn] = f2bf(v);
      }
    }
}

// ---------- per-column (sequence-axis) sum / sumsq via atomics ----------
__global__ __launch_bounds__(256) void k_colstats(const unsigned short* __restrict__ X,
                                                  float* __restrict__ stats,
                                                  int rowW, int statoff){
  int c = blockIdx.x*512 + threadIdx.x*2;
  int b = blockIdx.z;
  int r0 = blockIdx.y*128;
  const unsigned short* p = X + (size_t)(b*NS + r0)*rowW + c;
  float s0=0.f,s1=0.f,q0=0.f,q1=0.f;
  for (int r=0;r<128;++r){
    unsigned int v = *reinterpret_cast<const unsigned int*>(p);
    float x0 = bf2f((unsigned short)(v & 0xffffu));
    float x1 = bf2f((unsigned short)(v >> 16));
    s0 += x0; q0 += x0*x0; s1 += x1; q1 += x1*x1;
    p += rowW;
  }
  float* sp = stats + (size_t)(b*3*ND + statoff + c)*2;
  atomicAdd(sp+0, s0); atomicAdd(sp+1, q0);
  atomicAdd(sp+2, s1); atomicAdd(sp+3, q1);
}

// Per (b, col<ND): q slot gets COMBINED scale invq*invK*0.125*log2e (K's
// mean-subtraction cancels in softmax; its scale folds into q). V slot as-is.
// K slot of sf left unwritten (nothing reads it).
__global__ __launch_bounds__(256) void k_statsfinal(const float* __restrict__ stats,
                                                    float2* __restrict__ sf){
  int t = blockIdx.x*256 + threadIdx.x;   // 0..4095
  int b = t >> 10, c = t & 1023;
  const float* sb = stats + (size_t)b*3*ND*2;
  float qs = sb[c*2], qq = sb[c*2+1];
  float ks = sb[(ND+c)*2], kq = sb[(ND+c)*2+1];
  float vs = sb[(2*ND+c)*2], vq = sb[(2*ND+c)*2+1];
  float mq = qs*(1.0f/NS);
  float invq = 1.0f/(sqrtf(fmaxf(qq*(1.0f/NS)-mq*mq, 0.0f)) + EPSN);
  float mk = ks*(1.0f/NS);
  float invk = 1.0f/(sqrtf(fmaxf(kq*(1.0f/NS)-mk*mk, 0.0f)) + EPSN);
  float mv = vs*(1.0f/NS);
  float invv = 1.0f/(sqrtf(fmaxf(vq*(1.0f/NS)-mv*mv, 0.0f)) + EPSN);
  float s = invq*invk*0.125f*1.44269504088896340736f;
  sf[(size_t)b*3*ND + c] = make_float2(s, -mq*s);
  sf[(size_t)b*3*ND + 2*ND + c] = make_float2(invv, -mv*invv);
}

// ---------- in-place normalize of a [rows][rowW] bf16 buffer, cols [0,1024) ----------
__global__ __launch_bounds__(256) void k_norm(unsigned short* __restrict__ X,
                                              const float2* __restrict__ sf,
                                              int rowW, int statoff){
  int idx = blockIdx.x*256 + threadIdx.x;
  int row = idx >> 8;
  int c = (idx & 255)*4;
  int b = row >> 11;
  unsigned short* p = X + (size_t)row*rowW + c;
  uint2 v = *reinterpret_cast<const uint2*>(p);
  const float2* s = sf + (size_t)b*3*ND + statoff + c;
  float2 s0=s[0], s1=s[1], s2=s[2], s3=s[3];
  unsigned int lo = (unsigned int)f2bf(bf2f((unsigned short)(v.x & 0xffffu))*s0.x + s0.y)
                  | ((unsigned int)f2bf(bf2f((unsigned short)(v.x >> 16))*s1.x + s1.y) << 16);
  unsigned int hi = (unsigned int)f2bf(bf2f((unsigned short)(v.y & 0xffffu))*s2.x + s2.y)
                  | ((unsigned int)f2bf(bf2f((unsigned short)(v.y >> 16))*s3.x + s3.y) << 16);
  *reinterpret_cast<uint2*>(p) = make_uint2(lo, hi);
}

// ---------- V-half normalize + transpose: kv[..,D+h*64+c] -> vt[B,H,HD,S] ----------
__global__ __launch_bounds__(256) void k_vtrans(const unsigned short* __restrict__ kv,
                                                unsigned short* __restrict__ vt,
                                                const float2* __restrict__ sf){
  __shared__ unsigned short t[64][72];
  int s0 = blockIdx.x*64, h = blockIdx.y, b = blockIdx.z;
  int tid = threadIdx.x;
  int rr = tid >> 4;
  int cc = (tid & 15)*4;
  const float2* sp = sf + (size_t)b*3*ND + 2*ND + h*64 + cc;
  float2 f0=sp[0], f1=sp[1], f2v=sp[2], f3=sp[3];
  #pragma unroll
  for (int i=0;i<4;++i){
    int r = i*16 + rr;
    const unsigned short* p = kv + (size_t)(b*NS + s0 + r)*2048 + ND + h*64 + cc;
    uint2 v = *reinterpret_cast<const uint2*>(p);
    t[cc+0][r] = f2bf(bf2f((unsigned short)(v.x & 0xffffu))*f0.x + f0.y);
    t[cc+1][r] = f2bf(bf2f((unsigned short)(v.x >> 16))*f1.x + f1.y);
    t[cc+2][r] = f2bf(bf2f((unsigned short)(v.y & 0xffffu))*f2v.x + f2v.y);
    t[cc+3][r] = f2bf(bf2f((unsigned short)(v.y >> 16))*f3.x + f3.y);
  }
  __syncthreads();
  int hd = tid >> 2, scn = (tid & 3)*16;
  __align__(16) unsigned short tmp[16];
  #pragma unroll
  for (int j=0;j<16;++j) tmp[j] = t[hd][scn+j];
  uint4* dst = reinterpret_cast<uint4*>(&vt[((size_t)(b*NH + h)*64 + hd)*NS + s0 + scn]);
  dst[0] = *reinterpret_cast<uint4*>(&tmp[0]);
  dst[1] = *reinterpret_cast<uint4*>(&tmp[8]);
}

// ---------- QK^T + softmax-numerator for one 32-row q-group ----------
__device__ __forceinline__ void qk_phase(const bf16x8 (&kb)[4][2],
                                         const bf16x8 (&qa)[2][2],
                                         float (&rs)[2],
                                         unsigned short* pl,
                                         int k0, int q0, int lr, int lg,
                                         bool masked){
  #pragma unroll
  for (int g=0; g<2; ++g){
    f32x4 sc[4];
    #pragma unroll
    for (int kc=0;kc<4;++kc){
      f32x4 a = {};
      a = MFMA16(kb[kc][0], qa[g][0], a);
      a = MFMA16(kb[kc][1], qa[g][1], a);
      sc[kc] = a;
    }
    const int qrow = q0 + g*16 + lr;
    float acc = 0.f;
    if (!masked){
      #pragma unroll
      for (int kc=0;kc<4;++kc)
        #pragma unroll
        for (int r=0;r<4;++r){
          float pv = __builtin_amdgcn_exp2f(sc[kc][r]);
          sc[kc][r] = pv; acc += pv;
        }
    } else {
      #pragma unroll
      for (int kc=0;kc<4;++kc)
        #pragma unroll
        for (int r=0;r<4;++r){
          int kcol = k0 + kc*16 + lg*4 + r;
          float pv = (kcol <= qrow) ? __builtin_amdgcn_exp2f(sc[kc][r]) : 0.f;
          sc[kc][r] = pv; acc += pv;
        }
    }
    rs[g] += acc;
    #pragma unroll
    for (int kc=0;kc<4;++kc){
      uint2 pk;
      pk.x = cvtpk(sc[kc][0], sc[kc][1]);
      pk.y = cvtpk(sc[kc][2], sc[kc][3]);
      *reinterpret_cast<uint2*>(pl + (g*16+lr)*72 + kc*16 + lg*4) = pk;
    }
  }
}

// ---------- causal attention: each wave owns q-group PAIR (i, 63-i) ----------
// Work per wave is EXACTLY 33 KV-iters for every i -> zero imbalance.
// Swapped MFMA operands throughout; no online max (scores bounded; scale and
// log2e pre-folded into q's normalization, K read RAW - its norm cancels).
__global__ __launch_bounds__(256) void k_attn(const unsigned short* __restrict__ qn,
                                              const unsigned short* __restrict__ kn,
                                              const unsigned short* __restrict__ vt,
                                              unsigned short* __restrict__ heads){
  __shared__ __align__(16) unsigned short plds[4][2][32][72];
  const int bid = blockIdx.x;             // 512 blocks
  const int xcd = bid & 7, j = bid >> 3;
  const int bh = xcd*8 + (j & 7);         // all 8 blocks of a (b,h) on one XCD
  const int p = j >> 3;                   // 0..7
  const int h = bh & 15, b = bh >> 4;
  const int tid = threadIdx.x, w = tid >> 6, l = tid & 63;
  const int lr = l & 15, lg = l >> 4;
  const int i = p*4 + w;                  // 0..31
  const int q0A = i*32, q0B = (63-i)*32;
  const int ktwA = (i >> 1) + 1, ktwB = ((63-i) >> 1) + 1;  // sum = 33

  const unsigned short* qpA = qn + (size_t)(b*NS + q0A + lr)*ND + h*64 + lg*8;
  const unsigned short* qpB = qn + (size_t)(b*NS + q0B + lr)*ND + h*64 + lg*8;
  bf16x8 qaA[2][2], qaB[2][2];
  qaA[0][0] = *reinterpret_cast<const bf16x8*>(qpA);
  qaA[0][1] = *reinterpret_cast<const bf16x8*>(qpA + 32);
  qaA[1][0] = *reinterpret_cast<const bf16x8*>(qpA + 16*ND);
  qaA[1][1] = *reinterpret_cast<const bf16x8*>(qpA + 16*ND + 32);
  qaB[0][0] = *reinterpret_cast<const bf16x8*>(qpB);
  qaB[0][1] = *reinterpret_cast<const bf16x8*>(qpB + 32);
  qaB[1][0] = *reinterpret_cast<const bf16x8*>(qpB + 16*ND);
  qaB[1][1] = *reinterpret_cast<const bf16x8*>(qpB + 16*ND + 32);

  f32x4 oA[2][4] = {}, oB[2][4] = {};
  float rsA[2] = {0.f, 0.f}, rsB[2] = {0.f, 0.f};
  const unsigned short* kbase = kn + (size_t)b*NS*2048 + h*64 + lg*8;
  const unsigned short* vbase = vt + ((size_t)(b*NH + h)*64 + lr)*NS + lg*8;
  unsigned short* plA = &plds[w][0][0][0];
  unsigned short* plB = &plds[w][1][0][0];

  for (int kt = 0; kt < ktwB; ++kt){
    const int k0 = kt*64;
    bf16x8 kb[4][2];
    #pragma unroll
    for (int kc=0;kc<4;++kc){
      const unsigned short* kp = kbase + (size_t)(k0 + kc*16 + lr)*2048;
      kb[kc][0] = *reinterpret_cast<const bf16x8*>(kp);
      kb[kc][1] = *reinterpret_cast<const bf16x8*>(kp + 32);
    }
    const bool actA = (kt < ktwA);
    qk_phase(kb, qaB, rsB, plB, k0, q0B, lr, lg, kt == ktwB-1);
    if (actA) qk_phase(kb, qaA, rsA, plA, k0, q0A, lr, lg, kt == ktwA-1);
    // V frags in regs BEFORE the LDS wait so PV doesn't eat their latency
    bf16x8 vb[4][2];
    #pragma unroll
    for (int dt=0;dt<4;++dt){
      const unsigned short* vp = vbase + (size_t)dt*16*NS + k0;
      vb[dt][0] = *reinterpret_cast<const bf16x8*>(vp);
      vb[dt][1] = *reinterpret_cast<const bf16x8*>(vp + 32);
    }
    asm volatile("s_waitcnt lgkmcnt(0)" ::: "memory");
    __builtin_amdgcn_sched_barrier(0);
    bf16x8 pfB[2][2];
    #pragma unroll
    for (int g=0; g<2; ++g){
      pfB[g][0] = *reinterpret_cast<const bf16x8*>(plB + (g*16+lr)*72 + lg*8);
      pfB[g][1] = *reinterpret_cast<const bf16x8*>(plB + (g*16+lr)*72 + 32 + lg*8);
    }
    #pragma unroll
    for (int dt=0; dt<4; ++dt){
      oB[0][dt] = MFMA16(vb[dt][0], pfB[0][0], oB[0][dt]);
      oB[0][dt] = MFMA16(vb[dt][1], pfB[0][1], oB[0][dt]);
      oB[1][dt] = MFMA16(vb[dt][0], pfB[1][0], oB[1][dt]);
      oB[1][dt] = MFMA16(vb[dt][1], pfB[1][1], oB[1][dt]);
    }
    if (actA){
      bf16x8 pfA[2][2];
      #pragma unroll
      for (int g=0; g<2; ++g){
        pfA[g][0] = *reinterpret_cast<const bf16x8*>(plA + (g*16+lr)*72 + lg*8);
        pfA[g][1] = *reinterpret_cast<const bf16x8*>(plA + (g*16+lr)*72 + 32 + lg*8);
      }
      #pragma unroll
      for (int dt=0; dt<4; ++dt){
        oA[0][dt] = MFMA16(vb[dt][0], pfA[0][0], oA[0][dt]);
        oA[0][dt] = MFMA16(vb[dt][1], pfA[0][1], oA[0][dt]);
        oA[1][dt] = MFMA16(vb[dt][0], pfA[1][0], oA[1][dt]);
        oA[1][dt] = MFMA16(vb[dt][1], pfA[1][1], oA[1][dt]);
      }
    }
  }

  #pragma unroll
  for (int g=0; g<2; ++g){
    rsA[g] += __shfl_xor(rsA[g], 16, 64); rsA[g] += __shfl_xor(rsA[g], 32, 64);
    rsB[g] += __shfl_xor(rsB[g], 16, 64); rsB[g] += __shfl_xor(rsB[g], 32, 64);
  }
  #pragma unroll
  for (int g=0; g<2; ++g){
    float invA = 1.0f/rsA[g], invB = 1.0f/rsB[g];
    #pragma unroll
    for (int dt=0; dt<4; ++dt){
      uint2 ovA, ovB;
      ovA.x = cvtpk(oA[g][dt][0]*invA, oA[g][dt][1]*invA);
      ovA.y = cvtpk(oA[g][dt][2]*invA, oA[g][dt][3]*invA);
      ovB.x = cvtpk(oB[g][dt][0]*invB, oB[g][dt][1]*invB);
      ovB.y = cvtpk(oB[g][dt][2]*invB, oB[g][dt][3]*invB);
      *reinterpret_cast<uint2*>(
        &heads[(size_t)(b*NS + q0A + g*16 + lr)*ND + h*64 + dt*16 + lg*4]) = ovA;
      *reinterpret_cast<uint2*>(
        &heads[(size_t)(b*NS + q0B + g*16 + lr)*ND + h*64 + dt*16 + lg*4]) = ovB;
    }
  }
}

extern "C" void kernel_launch(void* const* d_in, const int* in_sizes, int n_in,
                              void* d_out, int out_size, void* d_ws, size_t ws_size,
                              hipStream_t stream){
  (void)in_sizes; (void)n_in; (void)out_size; (void)ws_size;
  const float* query = (const float*)d_in[0];
  const float* value = (const float*)d_in[1];
  const float* Wq  = (const float*)d_in[3];
  const float* Wkv = (const float*)d_in[5];
  const float* Wo  = (const float*)d_in[7];
  const float* bo  = (const float*)d_in[8];

  char* ws = (char*)d_ws;
  unsigned short* qx    = (unsigned short*)(ws + 0);          // 16MB (aliased: vt later)
  unsigned short* vx    = (unsigned short*)(ws + 16777216);   // 16MB (aliased: heads later)
  unsigned short* wqt   = (unsigned short*)(ws + 33554432);   // 2MB
  unsigned short* wkvt  = (unsigned short*)(ws + 35651584);   // 4MB
  unsigned short* wot   = (unsigned short*)(ws + 39845888);   // 2MB
  unsigned short* qbuf  = (unsigned short*)(ws + 41943040);   // 16MB
  unsigned short* kvbuf = (unsigned short*)(ws + 58720256);   // 32MB
  float*          stats = (float*)(ws + 92274688);            // 96KB
  float2*         sfin  = (float2*)(ws + 92372992);           // 96KB
  unsigned short* vtb   = qx;
  unsigned short* heads = vx;

  hipMemsetAsync(stats, 0, NB*3*ND*2*sizeof(float), stream);
  k_cvt<<<8192, 256, 0, stream>>>((const float4*)query, (ushort4*)qx);
  k_cvt<<<8192, 256, 0, stream>>>((const float4*)value, (ushort4*)vx);
  k_wtrans<<<dim3(16,16), 256, 0, stream>>>(Wq, wqt, 1024, 1024);
  k_wtrans<<<dim3(32,16), 256, 0, stream>>>(Wkv, wkvt, 1024, 2048);
  k_wtrans<<<dim3(16,16), 256, 0, stream>>>(Wo, wot, 1024, 1024);
  k_gemm<0><<<dim3(8,64), 256, 0, stream>>>(qx, wqt, qbuf, nullptr, 1024, 1024);
  k_gemm<0><<<dim3(16,64), 256, 0, stream>>>(vx, wkvt, kvbuf, nullptr, 2048, 1024);
  k_colstats<<<dim3(2,16,4), 256, 0, stream>>>(qbuf, stats, 1024, 0);
  k_colstats<<<dim3(4,16,4), 256, 0, stream>>>(kvbuf, stats, 2048, 1024);
  k_statsfinal<<<16, 256, 0, stream>>>(stats, sfin);
  k_norm<<<8192, 256, 0, stream>>>(qbuf, sfin, 1024, 0);
  k_vtrans<<<dim3(32,16,4), 256, 0, stream>>>(kvbuf, vtb, sfin);
  k_attn<<<512, 256, 0, stream>>>(qbuf, kvbuf, vtb, heads);
  k_gemm<1><<<dim3(8,64), 256, 0, stream>>>(heads, wot, d_out, bo, 1024, 1024);
}